// Round 4
// baseline (169.262 us; speedup 1.0000x reference)
//
#include <hip/hip_runtime.h>
#include <math.h>

#define BATCH 32
#define HW    (512*512)
#define N4    (HW/4)
#define BPB   32     // blocks per batch (1024 total) -- round-2 proven config
#define TPB   256

// workspace layout (bytes)
#define WS_SSUM   0      // double [B][12]
#define WS_DSUM   3072   // double [B][3]
#define WS_COUNTS 3840   // uint   [B][3]
#define WS_DONE   4224   // uint   [1]
#define WS_BYTES  4352

__device__ __forceinline__ float waveReduce(float v) {
#pragma unroll
  for (int off = 32; off > 0; off >>= 1) v += __shfl_down(v, off, 64);
  return v;
}

// Pass 1: per-batch counts[1..3] and ssum[seg=1..3][4]
__global__ __launch_bounds__(TPB) void k_sums(const float* __restrict__ emb,
                                              const int*   __restrict__ lab,
                                              double*      __restrict__ ssum,
                                              unsigned int* __restrict__ counts) {
  const int b   = blockIdx.y;
  const int tid = threadIdx.x;
  const float4* e0 = (const float4*)emb + (size_t)(b*4 + 0) * N4;
  const float4* e1 = (const float4*)emb + (size_t)(b*4 + 1) * N4;
  const float4* e2 = (const float4*)emb + (size_t)(b*4 + 2) * N4;
  const float4* e3 = (const float4*)emb + (size_t)(b*4 + 3) * N4;
  const int4*   lp = (const int4*)lab + (size_t)b * N4;

  float s[3][4] = {{0,0,0,0},{0,0,0,0},{0,0,0,0}};
  float c[3] = {0.f, 0.f, 0.f};

  for (int i = blockIdx.x * TPB + tid; i < N4; i += BPB * TPB) {
    float4 v0 = e0[i], v1 = e1[i], v2 = e2[i], v3 = e3[i];
    int4 l4 = lp[i];
    const int ls[4] = {l4.x, l4.y, l4.z, l4.w};
    const float xs[4][4] = {{v0.x,v1.x,v2.x,v3.x},{v0.y,v1.y,v2.y,v3.y},
                            {v0.z,v1.z,v2.z,v3.z},{v0.w,v1.w,v2.w,v3.w}};
#pragma unroll
    for (int k = 0; k < 4; k++) {
      int l = ls[k];
#pragma unroll
      for (int seg = 0; seg < 3; seg++) {
        float m = (l == seg + 1) ? 1.0f : 0.0f;
        c[seg] += m;
#pragma unroll
        for (int d = 0; d < 4; d++) s[seg][d] += m * xs[k][d];
      }
    }
  }

  __shared__ float red[4][15];
  int wave = tid >> 6, lane = tid & 63;
  float vals[15];
#pragma unroll
  for (int seg = 0; seg < 3; seg++)
#pragma unroll
    for (int d = 0; d < 4; d++) vals[seg*4 + d] = s[seg][d];
#pragma unroll
  for (int k = 0; k < 3; k++) vals[12 + k] = c[k];
#pragma unroll
  for (int v = 0; v < 15; v++) {
    float r = waveReduce(vals[v]);
    if (lane == 0) red[wave][v] = r;
  }
  __syncthreads();
  if (tid < 15) {
    float t = red[0][tid] + red[1][tid] + red[2][tid] + red[3][tid];
    if (tid < 12) atomicAdd(&ssum[b*12 + tid], (double)t);
    else          atomicAdd(&counts[b*3 + (tid - 12)], (unsigned)(t + 0.5f));
  }
}

// Pass 2: mu prologue + per-pixel hinge + last-block final reduction
__global__ __launch_bounds__(TPB) void k_var(const float* __restrict__ emb,
                                             const int*   __restrict__ lab,
                                             double*      __restrict__ ssum,
                                             unsigned int* __restrict__ counts,
                                             double*      __restrict__ dsum,
                                             unsigned int* __restrict__ done,
                                             float*       __restrict__ out) {
  const int b   = blockIdx.y;
  const int tid = threadIdx.x;

  // mu for this batch (kernel boundary makes k_sums results visible to plain loads)
  float m1v[4], m2v[4], m3v[4];
  {
    unsigned c1 = counts[b*3+0], c2 = counts[b*3+1], c3 = counts[b*3+2];
    double s1 = (c1 > 0) ? (double)c1 : 1.0;
    double s2 = (c2 > 0) ? (double)c2 : 1.0;
    double s3 = (c3 > 0) ? (double)c3 : 1.0;
#pragma unroll
    for (int cc = 0; cc < 4; cc++) {
      m1v[cc] = (float)(ssum[b*12 + 0 + cc] / s1);
      m2v[cc] = (float)(ssum[b*12 + 4 + cc] / s2);
      m3v[cc] = (float)(ssum[b*12 + 8 + cc] / s3);
    }
  }

  const float4* e0 = (const float4*)emb + (size_t)(b*4 + 0) * N4;
  const float4* e1 = (const float4*)emb + (size_t)(b*4 + 1) * N4;
  const float4* e2 = (const float4*)emb + (size_t)(b*4 + 2) * N4;
  const float4* e3 = (const float4*)emb + (size_t)(b*4 + 3) * N4;
  const int4*   lp = (const int4*)lab + (size_t)b * N4;

  float a1 = 0.f, a2 = 0.f, a3 = 0.f;
  for (int i = blockIdx.x * TPB + tid; i < N4; i += BPB * TPB) {
    float4 v0 = e0[i], v1 = e1[i], v2 = e2[i], v3 = e3[i];
    int4 l4 = lp[i];
    const int ls[4] = {l4.x, l4.y, l4.z, l4.w};
    const float xs[4][4] = {{v0.x,v1.x,v2.x,v3.x},{v0.y,v1.y,v2.y,v3.y},
                            {v0.z,v1.z,v2.z,v3.z},{v0.w,v1.w,v2.w,v3.w}};
#pragma unroll
    for (int k = 0; k < 4; k++) {
      int l = ls[k];
      float m1 = (l == 1) ? 1.f : 0.f;
      float m2 = (l == 2) ? 1.f : 0.f;
      float m3 = (l == 3) ? 1.f : 0.f;
      float d0 = xs[k][0] - (m1*m1v[0] + m2*m2v[0] + m3*m3v[0]);
      float d1 = xs[k][1] - (m1*m1v[1] + m2*m2v[1] + m3*m3v[1]);
      float d2 = xs[k][2] - (m1*m1v[2] + m2*m2v[2] + m3*m3v[2]);
      float d3 = xs[k][3] - (m1*m1v[3] + m2*m2v[3] + m3*m3v[3]);
      float dsq = d0*d0 + d1*d1 + d2*d2 + d3*d3;
      float h = fmaxf(sqrtf(dsq) - 0.5f, 0.f);
      float hh = h * h;
      a1 += hh * m1; a2 += hh * m2; a3 += hh * m3;
    }
  }

  __shared__ float red[4][3];
  __shared__ bool last;
  int wave = tid >> 6, lane = tid & 63;
  float vals[3] = {a1, a2, a3};
#pragma unroll
  for (int v = 0; v < 3; v++) {
    float r = waveReduce(vals[v]);
    if (lane == 0) red[wave][v] = r;
  }
  __syncthreads();
  if (tid < 3) {
    float t = red[0][tid] + red[1][tid] + red[2][tid] + red[3][tid];
    atomicAdd(&dsum[b*3 + tid], (double)t);
  }
  __threadfence();
  if (tid == 0) {
    unsigned prev = atomicAdd(done, 1u);
    last = (prev == (unsigned)(BPB * BATCH - 1));
  }
  __syncthreads();
  if (!last) return;

  // ---- final reduction (one block) ----
  float loss = 0.f;
  if (tid < BATCH) {
    int bb = tid;
    // device-scope reads of cross-XCD atomically-written data
    unsigned cn[3]; double ds[3]; double ss[12];
#pragma unroll
    for (int k = 0; k < 3; k++) {
      cn[k] = atomicAdd(&counts[bb*3 + k], 0u);
      ds[k] = atomicAdd(&dsum[bb*3 + k], 0.0);
    }
#pragma unroll
    for (int k = 0; k < 12; k++) ss[k] = atomicAdd(&ssum[bb*12 + k], 0.0);

    float mu[4][4];
#pragma unroll
    for (int cc = 0; cc < 4; cc++) mu[0][cc] = 0.f;
#pragma unroll
    for (int s = 1; s < 4; s++) {
      double cs = (cn[s-1] > 0) ? (double)cn[s-1] : 1.0;
#pragma unroll
      for (int cc = 0; cc < 4; cc++) mu[s][cc] = (float)(ss[(s-1)*4 + cc] / cs);
    }
    float mnsum = 0.f; int msum = 0;
#pragma unroll
    for (int i = 0; i < 4; i++) {
#pragma unroll
      for (int j = 0; j < 4; j++) {
        float sabs = 0.f, nsq = 0.f;
#pragma unroll
        for (int cc = 0; cc < 4; cc++) {
          float bv = (mu[i][cc] != 0.f) ? mu[j][cc] : 0.f;
          float iv = (bv != 0.f) ? mu[i][cc] : 0.f;
          float df = bv - iv;
          sabs += fabsf(df);
          nsq  += df * df;
        }
        if (sabs != 0.f) {
          msum += 1;
          float t = fmaxf(6.0f - sqrtf(nsq), 0.f);
          mnsum += t * t;
        }
      }
    }
    float l_dist = (msum > 0) ? (mnsum / (float)msum) : 0.f;
    float rs = 0.f;
#pragma unroll
    for (int s = 0; s < 4; s++) {
      float nsq = 0.f;
#pragma unroll
      for (int cc = 0; cc < 4; cc++) nsq += mu[s][cc] * mu[s][cc];
      rs += sqrtf(nsq);
    }
    float lconst = l_dist + 0.001f * (rs * 0.25f);

    int npres = 0; float acc = 0.f;
#pragma unroll
    for (int s = 0; s < 3; s++) {
      if (cn[s] > 0) { npres++; acc += (float)(ds[s] / (double)cn[s]); }
    }
    float l_var = (npres > 0) ? acc / (float)npres : 0.f;
    loss = (npres > 0) ? (l_var + lconst) : 0.f;
  }
#pragma unroll
  for (int off = 32; off > 0; off >>= 1) loss += __shfl_down(loss, off, 64);
  if (tid == 0) out[0] = loss / (float)BATCH;
}

extern "C" void kernel_launch(void* const* d_in, const int* in_sizes, int n_in,
                              void* d_out, int out_size, void* d_ws, size_t ws_size,
                              hipStream_t stream) {
  const float* emb = (const float*)d_in[0];
  const int*   lab = (const int*)d_in[2];   // d_in[1] = y, unused by reference
  float* out = (float*)d_out;
  char* ws = (char*)d_ws;
  double*   ssum   = (double*)(ws + WS_SSUM);
  double*   dsum   = (double*)(ws + WS_DSUM);
  unsigned* counts = (unsigned*)(ws + WS_COUNTS);
  unsigned* done   = (unsigned*)(ws + WS_DONE);

  hipMemsetAsync(d_ws, 0, WS_BYTES, stream);

  dim3 grid(BPB, BATCH);
  k_sums<<<grid, TPB, 0, stream>>>(emb, lab, ssum, counts);
  k_var <<<grid, TPB, 0, stream>>>(emb, lab, ssum, counts, dsum, done, out);
}

// Round 5
// 72.837 us; speedup vs baseline: 2.3238x; 2.3238x over previous
//
#include <hip/hip_runtime.h>
#include <math.h>

#define BATCH 32
#define HW    (512*512)
#define N4    (HW/4)
#define BPB   32
#define TPB   256

// workspace layout (bytes)
#define WS_SSUM   0      // double [B][12]
#define WS_DSUM   3072   // double [B][3]
#define WS_COUNTS 3840   // uint   [B][3]
#define WS_BYTES  4224

__device__ __forceinline__ float waveReduce(float v) {
#pragma unroll
  for (int off = 32; off > 0; off >>= 1) v += __shfl_down(v, off, 64);
  return v;
}

// Pass 1: per-batch counts[1..3] and ssum[seg=1..3][4]
__global__ __launch_bounds__(TPB) void k_sums(const float* __restrict__ emb,
                                              const int*   __restrict__ lab,
                                              double*      __restrict__ ssum,
                                              unsigned int* __restrict__ counts) {
  const int b   = blockIdx.y;
  const int tid = threadIdx.x;
  const float4* e0 = (const float4*)emb + (size_t)(b*4 + 0) * N4;
  const float4* e1 = (const float4*)emb + (size_t)(b*4 + 1) * N4;
  const float4* e2 = (const float4*)emb + (size_t)(b*4 + 2) * N4;
  const float4* e3 = (const float4*)emb + (size_t)(b*4 + 3) * N4;
  const int4*   lp = (const int4*)lab + (size_t)b * N4;

  float s[3][4] = {{0,0,0,0},{0,0,0,0},{0,0,0,0}};
  float c[3] = {0.f, 0.f, 0.f};

  for (int i = blockIdx.x * TPB + tid; i < N4; i += BPB * TPB) {
    float4 v0 = e0[i], v1 = e1[i], v2 = e2[i], v3 = e3[i];
    int4 l4 = lp[i];
    const int ls[4] = {l4.x, l4.y, l4.z, l4.w};
    const float xs[4][4] = {{v0.x,v1.x,v2.x,v3.x},{v0.y,v1.y,v2.y,v3.y},
                            {v0.z,v1.z,v2.z,v3.z},{v0.w,v1.w,v2.w,v3.w}};
#pragma unroll
    for (int k = 0; k < 4; k++) {
      int l = ls[k];
#pragma unroll
      for (int seg = 0; seg < 3; seg++) {
        float m = (l == seg + 1) ? 1.0f : 0.0f;
        c[seg] += m;
#pragma unroll
        for (int d = 0; d < 4; d++) s[seg][d] += m * xs[k][d];
      }
    }
  }

  __shared__ float red[4][15];
  int wave = tid >> 6, lane = tid & 63;
  float vals[15];
#pragma unroll
  for (int seg = 0; seg < 3; seg++)
#pragma unroll
    for (int d = 0; d < 4; d++) vals[seg*4 + d] = s[seg][d];
#pragma unroll
  for (int k = 0; k < 3; k++) vals[12 + k] = c[k];
#pragma unroll
  for (int v = 0; v < 15; v++) {
    float r = waveReduce(vals[v]);
    if (lane == 0) red[wave][v] = r;
  }
  __syncthreads();
  if (tid < 15) {
    float t = red[0][tid] + red[1][tid] + red[2][tid] + red[3][tid];
    if (tid < 12) atomicAdd(&ssum[b*12 + tid], (double)t);
    else          atomicAdd(&counts[b*3 + (tid - 12)], (unsigned)(t + 0.5f));
  }
}

// Pass 2: mu prologue (LDS broadcast, no fence) + per-pixel hinge
__global__ __launch_bounds__(TPB) void k_var(const float* __restrict__ emb,
                                             const int*   __restrict__ lab,
                                             const double* __restrict__ ssum,
                                             const unsigned int* __restrict__ counts,
                                             double*      __restrict__ dsum) {
  const int b   = blockIdx.y;
  const int tid = threadIdx.x;

  __shared__ float smu[12];
  if (tid < 12) {
    unsigned cnt = counts[b*3 + (tid >> 2)];
    double cs = (cnt > 0) ? (double)cnt : 1.0;
    smu[tid] = (float)(ssum[b*12 + tid] / cs);
  }
  __syncthreads();
  float m1v[4], m2v[4], m3v[4];
#pragma unroll
  for (int cc = 0; cc < 4; cc++) {
    m1v[cc] = smu[0 + cc];
    m2v[cc] = smu[4 + cc];
    m3v[cc] = smu[8 + cc];
  }

  const float4* e0 = (const float4*)emb + (size_t)(b*4 + 0) * N4;
  const float4* e1 = (const float4*)emb + (size_t)(b*4 + 1) * N4;
  const float4* e2 = (const float4*)emb + (size_t)(b*4 + 2) * N4;
  const float4* e3 = (const float4*)emb + (size_t)(b*4 + 3) * N4;
  const int4*   lp = (const int4*)lab + (size_t)b * N4;

  float a1 = 0.f, a2 = 0.f, a3 = 0.f;
  for (int i = blockIdx.x * TPB + tid; i < N4; i += BPB * TPB) {
    float4 v0 = e0[i], v1 = e1[i], v2 = e2[i], v3 = e3[i];
    int4 l4 = lp[i];
    const int ls[4] = {l4.x, l4.y, l4.z, l4.w};
    const float xs[4][4] = {{v0.x,v1.x,v2.x,v3.x},{v0.y,v1.y,v2.y,v3.y},
                            {v0.z,v1.z,v2.z,v3.z},{v0.w,v1.w,v2.w,v3.w}};
#pragma unroll
    for (int k = 0; k < 4; k++) {
      int l = ls[k];
      float m1 = (l == 1) ? 1.f : 0.f;
      float m2 = (l == 2) ? 1.f : 0.f;
      float m3 = (l == 3) ? 1.f : 0.f;
      float d0 = xs[k][0] - (m1*m1v[0] + m2*m2v[0] + m3*m3v[0]);
      float d1 = xs[k][1] - (m1*m1v[1] + m2*m2v[1] + m3*m3v[1]);
      float d2 = xs[k][2] - (m1*m1v[2] + m2*m2v[2] + m3*m3v[2]);
      float d3 = xs[k][3] - (m1*m1v[3] + m2*m2v[3] + m3*m3v[3]);
      float dsq = d0*d0 + d1*d1 + d2*d2 + d3*d3;
      float h = fmaxf(sqrtf(dsq) - 0.5f, 0.f);
      float hh = h * h;
      a1 += hh * m1; a2 += hh * m2; a3 += hh * m3;
    }
  }

  __shared__ float red[4][3];
  int wave = tid >> 6, lane = tid & 63;
  float vals[3] = {a1, a2, a3};
#pragma unroll
  for (int v = 0; v < 3; v++) {
    float r = waveReduce(vals[v]);
    if (lane == 0) red[wave][v] = r;
  }
  __syncthreads();
  if (tid < 3) {
    float t = red[0][tid] + red[1][tid] + red[2][tid] + red[3][tid];
    atomicAdd(&dsum[b*3 + tid], (double)t);
  }
}

// Final: mu/l_dist/l_reg/l_var per batch, mean over batches
__global__ void k_final(const double* __restrict__ ssum, const double* __restrict__ dsum,
                        const unsigned* __restrict__ counts, float* __restrict__ out) {
  int tid = threadIdx.x;
  float loss = 0.f;
  if (tid < BATCH) {
    int b = tid;
    unsigned cn[3];
#pragma unroll
    for (int k = 0; k < 3; k++) cn[k] = counts[b*3 + k];

    float mu[4][4];
#pragma unroll
    for (int cc = 0; cc < 4; cc++) mu[0][cc] = 0.f;
#pragma unroll
    for (int s = 1; s < 4; s++) {
      double cs = (cn[s-1] > 0) ? (double)cn[s-1] : 1.0;
#pragma unroll
      for (int cc = 0; cc < 4; cc++) mu[s][cc] = (float)(ssum[b*12 + (s-1)*4 + cc] / cs);
    }
    float mnsum = 0.f; int msum = 0;
#pragma unroll
    for (int i = 0; i < 4; i++) {
#pragma unroll
      for (int j = 0; j < 4; j++) {
        float sabs = 0.f, nsq = 0.f;
#pragma unroll
        for (int cc = 0; cc < 4; cc++) {
          float bv = (mu[i][cc] != 0.f) ? mu[j][cc] : 0.f;
          float iv = (bv != 0.f) ? mu[i][cc] : 0.f;
          float df = bv - iv;
          sabs += fabsf(df);
          nsq  += df * df;
        }
        if (sabs != 0.f) {
          msum += 1;
          float t = fmaxf(6.0f - sqrtf(nsq), 0.f);
          mnsum += t * t;
        }
      }
    }
    float l_dist = (msum > 0) ? (mnsum / (float)msum) : 0.f;
    float rs = 0.f;
#pragma unroll
    for (int s = 0; s < 4; s++) {
      float nsq = 0.f;
#pragma unroll
      for (int cc = 0; cc < 4; cc++) nsq += mu[s][cc] * mu[s][cc];
      rs += sqrtf(nsq);
    }
    float lconst = l_dist + 0.001f * (rs * 0.25f);

    int npres = 0; float acc = 0.f;
#pragma unroll
    for (int s = 0; s < 3; s++) {
      if (cn[s] > 0) { npres++; acc += (float)(dsum[b*3 + s] / (double)cn[s]); }
    }
    float l_var = (npres > 0) ? acc / (float)npres : 0.f;
    loss = (npres > 0) ? (l_var + lconst) : 0.f;
  }
#pragma unroll
  for (int off = 32; off > 0; off >>= 1) loss += __shfl_down(loss, off, 64);
  if (tid == 0) out[0] = loss / (float)BATCH;
}

extern "C" void kernel_launch(void* const* d_in, const int* in_sizes, int n_in,
                              void* d_out, int out_size, void* d_ws, size_t ws_size,
                              hipStream_t stream) {
  const float* emb = (const float*)d_in[0];
  const int*   lab = (const int*)d_in[2];   // d_in[1] = y, unused by reference
  float* out = (float*)d_out;
  char* ws = (char*)d_ws;
  double*   ssum   = (double*)(ws + WS_SSUM);
  double*   dsum   = (double*)(ws + WS_DSUM);
  unsigned* counts = (unsigned*)(ws + WS_COUNTS);

  hipMemsetAsync(d_ws, 0, WS_BYTES, stream);

  dim3 grid(BPB, BATCH);
  k_sums<<<grid, TPB, 0, stream>>>(emb, lab, ssum, counts);
  k_var <<<grid, TPB, 0, stream>>>(emb, lab, ssum, counts, dsum);
  k_final<<<1, 64, 0, stream>>>(ssum, dsum, counts, out);
}